// Round 2
// baseline (361.286 us; speedup 1.0000x reference)
//
#include <hip/hip_runtime.h>

#define N_    8
#define C_    256
#define K_    7
#define HID_  10
#define OUTC_ 60
#define S_    16384
#define BN_EPS 1e-5f

// ---- workspace layout (float offsets) ----
#define OFF_NUM  0               // N*C*K = 14336
#define OFF_DEN  14336           // 56 -> pad 64   (num+den zeroed together)
#define OFF_WQK  14400           // N*C*8 = 16384
#define OFF_EB   30784           // 64
#define OFF_M2   30848           // N*60*7 = 3360 -> pad to 34240
#define OFF_WPT  34240           // 256*60 = 15360 (transposed Wp1, n-independent)
#define OFF_PART 49600           // 512*120 = 61440
#define OFF_SCL  111040          // 64
#define OFF_SHF  111104          // 64
// total 111168 floats = 445 KB

// ---------------- kernel A: fused class-softmax + pooling GEMM ----------------
// grid: n(8) x c-octet(32) x s-half(2) = 512 blocks
__global__ void __launch_bounds__(256) k_pool(
        const float* __restrict__ fea, const float* __restrict__ seg,
        float* __restrict__ num, float* __restrict__ den) {
    int b = blockIdx.x;
    int n = b >> 6, r = b & 63;
    int c0 = (r >> 1) * 8, sh = r & 1;
    int tid = threadIdx.x;
    const float* sp = seg + (size_t)n * K_ * S_ + sh * 8192;
    const float* fp = fea + ((size_t)n * C_ + c0) * S_ + sh * 8192;

    float acc[8][K_] = {};
    float dsum[K_] = {};
    for (int s = tid * 2; s < 8192; s += 512) {
        float2 e[K_];
        float mx = -1e30f, my = -1e30f;
#pragma unroll
        for (int k = 0; k < K_; k++) {
            e[k] = *(const float2*)(sp + (size_t)k * S_ + s);
            mx = fmaxf(mx, e[k].x); my = fmaxf(my, e[k].y);
        }
        float ax[K_], ay[K_], sumx = 0.f, sumy = 0.f;
#pragma unroll
        for (int k = 0; k < K_; k++) {
            ax[k] = __expf(e[k].x - mx); sumx += ax[k];
            ay[k] = __expf(e[k].y - my); sumy += ay[k];
        }
        float invx = 1.f / sumx, invy = 1.f / sumy;
#pragma unroll
        for (int k = 0; k < K_; k++) {
            ax[k] *= invx; ay[k] *= invy;
            dsum[k] += ax[k] + ay[k];
        }
#pragma unroll
        for (int c = 0; c < 8; c++) {
            float2 f = *(const float2*)(fp + (size_t)c * S_ + s);
#pragma unroll
            for (int k = 0; k < K_; k++) acc[c][k] += f.x * ax[k] + f.y * ay[k];
        }
    }
    __shared__ float red[4][63];
    int lane = tid & 63, wv = tid >> 6;
#pragma unroll
    for (int i = 0; i < 56; i++) {
        float v = acc[i / K_][i % K_];
        for (int off = 32; off; off >>= 1) v += __shfl_xor(v, off, 64);
        if (lane == 0) red[wv][i] = v;
    }
    if (c0 == 0) {
#pragma unroll
        for (int k = 0; k < K_; k++) {
            float v = dsum[k];
            for (int off = 32; off; off >>= 1) v += __shfl_xor(v, off, 64);
            if (lane == 0) red[wv][56 + k] = v;
        }
    }
    __syncthreads();
    if (tid < 56) {
        float v = red[0][tid] + red[1][tid] + red[2][tid] + red[3][tid];
        atomicAdd(&num[((size_t)n * C_ + c0 + tid / K_) * K_ + tid % K_], v);
    } else if (tid >= 56 && tid < 63 && c0 == 0) {
        float v = red[0][tid] + red[1][tid] + red[2][tid] + red[3][tid];
        atomicAdd(&den[n * K_ + (tid - 56)], v);
    }
}

// ---------------- kernel B: p_center -> query -> Wqk, ebias, M2, wp_t ----------------
__global__ void k_center(const float* __restrict__ num, const float* __restrict__ den,
                         const float* __restrict__ Wq, const float* __restrict__ bq,
                         const float* __restrict__ Wk, const float* __restrict__ bk,
                         const float* __restrict__ Wp,
                         float* __restrict__ wqk, float* __restrict__ eb,
                         float* __restrict__ m2, float* __restrict__ wpt) {
    int n = blockIdx.x, tid = threadIdx.x;
    __shared__ float pc[C_ * K_];     // [c][k]
    __shared__ float ql[HID_ * K_];   // [o][k]
    __shared__ float dinv[K_];
    if (tid < K_) dinv[tid] = 1.f / den[n * K_ + tid];
    __syncthreads();
    for (int i = tid; i < C_ * K_; i += 256)
        pc[i] = num[(size_t)n * C_ * K_ + i] * dinv[i % K_];
    __syncthreads();
    if (tid < HID_ * K_) {
        int o = tid / K_, k = tid % K_;
        float s = bq[o];
        for (int c = 0; c < C_; c++) s += Wq[o * C_ + c] * pc[c * K_ + k];
        ql[tid] = s;
    }
    __syncthreads();
    for (int i = tid; i < C_ * 8; i += 256) {
        int c = i >> 3, k = i & 7;
        float s = 0.f;
        if (k < K_)
            for (int o = 0; o < HID_; o++) s += ql[o * K_ + k] * Wk[o * C_ + c];
        wqk[(size_t)n * C_ * 8 + i] = s;
    }
    if (tid < K_) {
        float s = 0.f;
        for (int o = 0; o < HID_; o++) s += ql[o * K_ + tid] * bk[o];
        eb[n * K_ + tid] = s;
    }
    for (int i = tid; i < OUTC_ * K_; i += 256) {
        int o = i / K_, k = i % K_;
        float s = 0.f;
        for (int c = 0; c < C_; c++) s += Wp[o * 2 * C_ + C_ + c] * pc[c * K_ + k];
        m2[(size_t)n * OUTC_ * K_ + i] = s;
    }
    // transposed Wp1 [c][60] (n-independent; block 0 writes)
    if (n == 0) {
        for (int i = tid; i < C_ * OUTC_; i += 256) {
            int c = i / OUTC_, o = i - c * OUTC_;
            wpt[i] = Wp[o * (2 * C_) + c];
        }
    }
}

// ---------------- kernel C: fused energy/softmax/projection ----------------
// grid: n(8) x s-tile(64, 256 px each) = 512 blocks; 1 px/thread
__global__ void __launch_bounds__(256, 4) k_main(
        const float* __restrict__ fea, const float* __restrict__ wpt,
        const float* __restrict__ wqk, const float* __restrict__ ebias,
        const float* __restrict__ m2, float* __restrict__ y,
        float* __restrict__ part) {
    int blk = blockIdx.x;
    int n = blk >> 6, tile = blk & 63;
    int tid = threadIdx.x;
    __shared__ float wp_l[64 * OUTC_];   // one 64-c chunk of Wp1^T  (15360 B)
    __shared__ float wqk_l[C_ * 8];      // 8192 B
    __shared__ float m2_l[OUTC_ * K_];   // 1680 B
    __shared__ float eb_l[K_];
    __shared__ float red[4][120];

    const float* wq = wqk + (size_t)n * C_ * 8;
    for (int i = tid; i < C_ * 8; i += 256) wqk_l[i] = wq[i];
    for (int i = tid; i < OUTC_ * K_; i += 256) m2_l[i] = m2[(size_t)n * OUTC_ * K_ + i];
    if (tid < K_) eb_l[tid] = ebias[n * K_ + tid];
    __syncthreads();

    int px = tile * 256 + tid;
    const float* fp = fea + (size_t)n * C_ * S_ + px;

    float ya[OUTC_];
    float ek[K_];
#pragma unroll
    for (int o = 0; o < OUTC_; o++) ya[o] = 0.f;
#pragma unroll
    for (int k = 0; k < K_; k++) ek[k] = eb_l[k];

    float fbuf[8];
#pragma unroll
    for (int j = 0; j < 8; j++) fbuf[j] = fp[(size_t)j * S_];

    for (int ch = 0; ch < 4; ch++) {
        __syncthreads();
        {   // stage 64-c chunk of wp_t as float4 (960 vec4 over 256 threads)
            const float4* src = (const float4*)(wpt + ch * 64 * OUTC_);
            float4* dst = (float4*)wp_l;
            for (int i = tid; i < 64 * OUTC_ / 4; i += 256) dst[i] = src[i];
        }
        __syncthreads();
        int cbase = ch * 64;
        for (int cc = 0; cc < 64; cc += 8) {
#pragma unroll
            for (int j = 0; j < 8; j++) {
                int c = cbase + cc + j;
                float f = fbuf[j];
                fbuf[j] = fp[(size_t)((c + 8) & 255) * S_];   // prefetch 8 ahead
#pragma unroll
                for (int k = 0; k < K_; k++) ek[k] += wqk_l[c * 8 + k] * f;
                int cl = (cc + j) * OUTC_;
#pragma unroll
                for (int o = 0; o < OUTC_; o++) ya[o] += wp_l[cl + o] * f;
            }
        }
    }

    // softmax over 7 classes + M2 @ attention
    {
        float m = ek[0];
#pragma unroll
        for (int k = 1; k < K_; k++) m = fmaxf(m, ek[k]);
        float a[K_]; float sum = 0.f;
#pragma unroll
        for (int k = 0; k < K_; k++) { a[k] = __expf(ek[k] - m); sum += a[k]; }
        float inv = 1.f / sum;
#pragma unroll
        for (int k = 0; k < K_; k++) a[k] *= inv;
#pragma unroll
        for (int o = 0; o < OUTC_; o++) {
            float s = 0.f;
#pragma unroll
            for (int k = 0; k < K_; k++) s += m2_l[o * K_ + k] * a[k];
            ya[o] += s;
        }
    }

    // store pre-BN y + BN partial sums
    float* yp = y + (size_t)n * OUTC_ * S_ + px;
    int lane = tid & 63, wv = tid >> 6;
#pragma unroll
    for (int o = 0; o < OUTC_; o++) {
        float v = ya[o];
        yp[(size_t)o * S_] = v;
        float sm = v, sq = v * v;
        for (int off = 32; off; off >>= 1) {
            sm += __shfl_xor(sm, off, 64);
            sq += __shfl_xor(sq, off, 64);
        }
        if (lane == 0) { red[wv][o] = sm; red[wv][60 + o] = sq; }
    }
    __syncthreads();
    if (tid < 120)
        part[(size_t)blk * 120 + tid] =
            red[0][tid] + red[1][tid] + red[2][tid] + red[3][tid];
}

// ---------------- kernel D: BN statistics ----------------
__global__ void k_bn(const float* __restrict__ part, const float* __restrict__ gamma,
                     const float* __restrict__ beta, float* __restrict__ scl,
                     float* __restrict__ shf) {
    int t = threadIdx.x & 127, q = threadIdx.x >> 7;   // 512 threads
    __shared__ float red[4][120];
    __shared__ float tot[120];
    if (t < 120) {
        float s = 0.f;
        for (int b = q * 128; b < q * 128 + 128; b++) s += part[(size_t)b * 120 + t];
        red[q][t] = s;
    }
    __syncthreads();
    if (threadIdx.x < 120)
        tot[threadIdx.x] = red[0][threadIdx.x] + red[1][threadIdx.x] +
                           red[2][threadIdx.x] + red[3][threadIdx.x];
    __syncthreads();
    if (threadIdx.x < OUTC_) {
        const float invn = 1.f / (float)(N_ * S_);
        float mean = tot[threadIdx.x] * invn;
        float var = tot[60 + threadIdx.x] * invn - mean * mean;
        float sc = gamma[threadIdx.x] * rsqrtf(var + BN_EPS);
        scl[threadIdx.x] = sc;
        shf[threadIdx.x] = beta[threadIdx.x] - mean * sc;
    }
}

// ---------------- kernel E: in-place BN apply + ReLU ----------------
__global__ void k_apply(float* __restrict__ y, const float* __restrict__ scl,
                        const float* __restrict__ shf) {
    int idx = blockIdx.x * 256 + threadIdx.x;          // float4 index
    int o = (idx >> 12) % OUTC_;
    float4 v = ((const float4*)y)[idx];
    float a = scl[o], b = shf[o];
    v.x = fmaxf(v.x * a + b, 0.f);
    v.y = fmaxf(v.y * a + b, 0.f);
    v.z = fmaxf(v.z * a + b, 0.f);
    v.w = fmaxf(v.w * a + b, 0.f);
    ((float4*)y)[idx] = v;
}

extern "C" void kernel_launch(void* const* d_in, const int* in_sizes, int n_in,
                              void* d_out, int out_size, void* d_ws, size_t ws_size,
                              hipStream_t stream) {
    const float* p_fea = (const float*)d_in[0];
    const float* p_seg = (const float*)d_in[1];
    const float* Wq    = (const float*)d_in[2];
    const float* bq    = (const float*)d_in[3];
    const float* Wk    = (const float*)d_in[4];
    const float* bk    = (const float*)d_in[5];
    const float* Wp    = (const float*)d_in[6];
    const float* gamma = (const float*)d_in[7];
    const float* beta  = (const float*)d_in[8];

    float* ws   = (float*)d_ws;
    float* num  = ws + OFF_NUM;
    float* den  = ws + OFF_DEN;
    float* wqk  = ws + OFF_WQK;
    float* eb   = ws + OFF_EB;
    float* m2   = ws + OFF_M2;
    float* wpt  = ws + OFF_WPT;
    float* part = ws + OFF_PART;
    float* scl  = ws + OFF_SCL;
    float* shf  = ws + OFF_SHF;
    float* ybuf = (float*)d_out;

    hipMemsetAsync(num, 0, 14400 * sizeof(float), stream);   // num + den
    k_pool<<<512, 256, 0, stream>>>(p_fea, p_seg, num, den);
    k_center<<<8, 256, 0, stream>>>(num, den, Wq, bq, Wk, bk, Wp, wqk, eb, m2, wpt);
    k_main<<<512, 256, 0, stream>>>(p_fea, wpt, wqk, eb, m2, ybuf, part);
    k_bn<<<1, 512, 0, stream>>>(part, gamma, beta, scl, shf);
    k_apply<<<(N_ * OUTC_ * S_ / 4) / 256, 256, 0, stream>>>(ybuf, scl, shf);
}